// Round 1
// baseline (130.581 us; speedup 1.0000x reference)
//
#include <hip/hip_runtime.h>
#include <hip/hip_bf16.h>

#define LOG2E 1.4426950408889634f
#define LN2   0.6931471805599453f

constexpr int Bn = 64, Sn = 512, Hn = 1024, Ln = 9;

__device__ __forceinline__ float fexp2(float x) {
    float r; asm("v_exp_f32 %0, %1" : "=v"(r) : "v"(x)); return r;
}
__device__ __forceinline__ float flog2(float x) {
    float r; asm("v_log_f32 %0, %1" : "=v"(r) : "v"(x)); return r;
}

// ---------------- Kernel 1: emissions = hidden @ W^T + b  (32768 x 9) ----------------
// 1024 blocks x 256 threads = 4096 waves; each wave computes 8 rows.
// W slice held in registers (9 x float4 per lane per pass), 4 passes over H.
__global__ __launch_bounds__(256) void emis_kernel(
    const float* __restrict__ hidden, const float* __restrict__ W,
    const float* __restrict__ bias, float* __restrict__ emis)
{
    const int lane = threadIdx.x & 63;
    const int gw   = blockIdx.x * 4 + (threadIdx.x >> 6);
    const int r0   = gw * 8;

    float acc[8][Ln];
    #pragma unroll
    for (int r = 0; r < 8; ++r)
        #pragma unroll
        for (int l = 0; l < Ln; ++l) acc[r][l] = 0.f;

    #pragma unroll 1
    for (int p = 0; p < 4; ++p) {
        const int h0 = p * 256 + lane * 4;   // float index into H
        float4 wv[Ln];
        #pragma unroll
        for (int l = 0; l < Ln; ++l)
            wv[l] = *(const float4*)(W + l * Hn + h0);
        #pragma unroll
        for (int r = 0; r < 8; ++r) {
            float4 h = *(const float4*)(hidden + (size_t)(r0 + r) * Hn + h0);
            #pragma unroll
            for (int l = 0; l < Ln; ++l) {
                acc[r][l] = fmaf(h.x, wv[l].x, acc[r][l]);
                acc[r][l] = fmaf(h.y, wv[l].y, acc[r][l]);
                acc[r][l] = fmaf(h.z, wv[l].z, acc[r][l]);
                acc[r][l] = fmaf(h.w, wv[l].w, acc[r][l]);
            }
        }
    }

    // butterfly reduce each of the 72 partials across the 64 lanes
    #pragma unroll
    for (int r = 0; r < 8; ++r)
        #pragma unroll
        for (int l = 0; l < Ln; ++l)
            #pragma unroll
            for (int off = 32; off; off >>= 1)
                acc[r][l] += __shfl_xor(acc[r][l], off);

    if (lane == 0) {
        float* o = emis + (size_t)r0 * Ln;
        #pragma unroll
        for (int r = 0; r < 8; ++r)
            #pragma unroll
            for (int l = 0; l < Ln; ++l)
                o[r * Ln + l] = acc[r][l] + bias[l];
    }
}

// ---------------- Kernel 2: per-batch CRF score + forward recursion ----------------
// 64 blocks x 64 threads (1 wave per batch). log2-domain recursion,
// pivot-based logsumexp (no max tree), LDS-staged emissions, prefetch e[t+1].
__global__ __launch_bounds__(64) void crf_kernel(
    const float* __restrict__ emis, const float* __restrict__ st,
    const float* __restrict__ et,   const float* __restrict__ T,
    const int* __restrict__ labels, const int* __restrict__ mask,
    float* __restrict__ llh)
{
    __shared__ __align__(16) float e2s[Sn * Ln];   // emissions * log2(e)
    const int b    = blockIdx.x;
    const int lane = threadIdx.x;

    const float* eb = emis + (size_t)b * Sn * Ln;
    // stage emissions into LDS, scaled to log2 domain (float4: 4608 = 1152*4)
    {
        const float4* src = (const float4*)eb;
        float4*       dst = (float4*)e2s;
        for (int i = lane; i < (Sn * Ln) / 4; i += 64) {
            float4 v = src[i];
            v.x *= LOG2E; v.y *= LOG2E; v.z *= LOG2E; v.w *= LOG2E;
            dst[i] = v;
        }
    }

    const int* mb = mask + b * Sn;
    const int* lb = labels + b * Sn;

    // sequence length (mask is monotone: arange < length)
    int sl = 0;
    for (int t = lane; t < Sn; t += 64) sl += mb[t];
    #pragma unroll
    for (int off = 32; off; off >>= 1) sl += __shfl_xor(sl, off);

    // numerator score (natural log domain), read emissions from global (L2-hot)
    float sc = 0.f;
    for (int t = lane; t < sl; t += 64) {
        int lt = lb[t];
        sc += eb[t * Ln + lt];
        if (t >= 1) sc += T[lb[t - 1] * Ln + lt];
    }
    #pragma unroll
    for (int off = 32; off; off >>= 1) sc += __shfl_xor(sc, off);

    // per-lane transition column (lane j holds T[:,j] * log2e)
    float tcol[Ln];
    #pragma unroll
    for (int i = 0; i < Ln; ++i) tcol[i] = (lane < Ln) ? T[i * Ln + lane] * LOG2E : 0.f;

    float alpha[Ln];
    #pragma unroll
    for (int i = 0; i < Ln; ++i) alpha[i] = st[i] * LOG2E;

    __syncthreads();

    #pragma unroll
    for (int i = 0; i < Ln; ++i) alpha[i] += e2s[i];   // alpha0

    const int lidx = (lane < Ln) ? lane : 0;
    float ecur = e2s[Ln + lidx];                        // e[t=1]
    for (int t = 1; t < sl; ++t) {
        float enxt = (t + 1 < sl) ? e2s[(t + 1) * Ln + lidx] : 0.f;  // prefetch
        float s[Ln];
        #pragma unroll
        for (int i = 0; i < Ln; ++i) s[i] = alpha[i] + tcol[i];
        const float p = s[0];
        float x1 = fexp2(s[1] - p), x2 = fexp2(s[2] - p);
        float x3 = fexp2(s[3] - p), x4 = fexp2(s[4] - p);
        float x5 = fexp2(s[5] - p), x6 = fexp2(s[6] - p);
        float x7 = fexp2(s[7] - p), x8 = fexp2(s[8] - p);
        float sum = (((x1 + x2) + (x3 + x4)) + ((x5 + x6) + (x7 + x8))) + 1.0f;
        float aj = p + flog2(sum) + ecur;   // new alpha for state j = lane
        #pragma unroll
        for (int i = 0; i < Ln; ++i) alpha[i] = __shfl(aj, i);
        ecur = enxt;
    }

    // logZ = ln-domain logsumexp(alpha + end_transitions)
    float z[Ln];
    #pragma unroll
    for (int i = 0; i < Ln; ++i) z[i] = alpha[i] + et[i] * LOG2E;
    const float p = z[0];
    float sum = 1.0f;
    #pragma unroll
    for (int i = 1; i < Ln; ++i) sum += fexp2(z[i] - p);
    const float logZ = (p + flog2(sum)) * LN2;

    if (lane == 0) {
        float total = sc + st[lb[0]] + et[lb[sl - 1]];
        llh[b] = total - logZ;
    }
}

// ---------------- Kernel 3: loss = -mean(llh) ----------------
__global__ __launch_bounds__(64) void loss_kernel(const float* __restrict__ llh,
                                                  float* __restrict__ out)
{
    float v = llh[threadIdx.x];
    #pragma unroll
    for (int off = 32; off; off >>= 1) v += __shfl_xor(v, off);
    if (threadIdx.x == 0) out[0] = -v * (1.0f / 64.0f);
}

extern "C" void kernel_launch(void* const* d_in, const int* in_sizes, int n_in,
                              void* d_out, int out_size, void* d_ws, size_t ws_size,
                              hipStream_t stream) {
    const float* hidden = (const float*)d_in[0];
    const float* W      = (const float*)d_in[1];
    const float* bias   = (const float*)d_in[2];
    const float* st     = (const float*)d_in[3];
    const float* et     = (const float*)d_in[4];
    const float* T      = (const float*)d_in[5];
    const int*   labels = (const int*)d_in[6];
    const int*   mask   = (const int*)d_in[7];

    float* emis = (float*)d_ws;                       // 32768 * 9 floats
    float* llh  = emis + (size_t)Bn * Sn * Ln;        // 64 floats

    emis_kernel<<<1024, 256, 0, stream>>>(hidden, W, bias, emis);
    crf_kernel<<<Bn, 64, 0, stream>>>(emis, st, et, T, labels, mask, llh);
    loss_kernel<<<1, 64, 0, stream>>>(llh, (float*)d_out);
}

// Round 2
// 74.604 us; speedup vs baseline: 1.7503x; 1.7503x over previous
//
#include <hip/hip_runtime.h>
#include <hip/hip_bf16.h>

#define LOG2E 1.4426950408889634f
#define LN2   0.6931471805599453f

constexpr int Bn = 64, Sn = 512, Hn = 1024, Ln = 9;
constexpr int CL = 16;          // matrix steps per chunk
constexpr int NC = 32;          // chunks per batch (covers steps 1..511)

__device__ __forceinline__ float fexp2(float x) {
    float r; asm("v_exp_f32 %0, %1" : "=v"(r) : "v"(x)); return r;
}
__device__ __forceinline__ float flog2(float x) {
    float r; asm("v_log_f32 %0, %1" : "=v"(r) : "v"(x)); return r;
}
__device__ __forceinline__ float max9(const float* s) {
    return fmaxf(fmaxf(fmaxf(s[0], s[1]), fmaxf(s[2], s[3])),
                 fmaxf(fmaxf(s[4], s[5]), fmaxf(s[6], fmaxf(s[7], s[8]))));
}

// ---------------- Kernel 1: emissions = hidden @ W^T + b  (32768 x 9) ----------------
__global__ __launch_bounds__(256) void emis_kernel(
    const float* __restrict__ hidden, const float* __restrict__ W,
    const float* __restrict__ bias, float* __restrict__ emis)
{
    const int lane = threadIdx.x & 63;
    const int gw   = blockIdx.x * 4 + (threadIdx.x >> 6);
    const int r0   = gw * 8;

    float acc[8][Ln];
    #pragma unroll
    for (int r = 0; r < 8; ++r)
        #pragma unroll
        for (int l = 0; l < Ln; ++l) acc[r][l] = 0.f;

    #pragma unroll 1
    for (int p = 0; p < 4; ++p) {
        const int h0 = p * 256 + lane * 4;
        float4 wv[Ln];
        #pragma unroll
        for (int l = 0; l < Ln; ++l)
            wv[l] = *(const float4*)(W + l * Hn + h0);
        #pragma unroll
        for (int r = 0; r < 8; ++r) {
            float4 h = *(const float4*)(hidden + (size_t)(r0 + r) * Hn + h0);
            #pragma unroll
            for (int l = 0; l < Ln; ++l) {
                acc[r][l] = fmaf(h.x, wv[l].x, acc[r][l]);
                acc[r][l] = fmaf(h.y, wv[l].y, acc[r][l]);
                acc[r][l] = fmaf(h.z, wv[l].z, acc[r][l]);
                acc[r][l] = fmaf(h.w, wv[l].w, acc[r][l]);
            }
        }
    }

    #pragma unroll
    for (int r = 0; r < 8; ++r)
        #pragma unroll
        for (int l = 0; l < Ln; ++l)
            #pragma unroll
            for (int off = 32; off; off >>= 1)
                acc[r][l] += __shfl_xor(acc[r][l], off);

    if (lane == 0) {
        float* o = emis + (size_t)r0 * Ln;
        #pragma unroll
        for (int r = 0; r < 8; ++r)
            #pragma unroll
            for (int l = 0; l < Ln; ++l)
                o[r * Ln + l] = acc[r][l] + bias[l];
    }
}

// ---------------- Kernel 2a: per-chunk transfer matrices (log2 domain) ----------------
// lane = (batch b, chunk c, row i). Row i of the chunk's 9x9 log-semiring matrix
// product updates with ZERO cross-lane traffic: row_i(P*M) = row_i(P) (x) M.
// Per step: 9 exp2 + 9 log2 + 81 FMA (E = exp(T) precomputed in registers).
__global__ __launch_bounds__(256) void chunk_kernel(
    const float* __restrict__ emis, const float* __restrict__ T,
    const int* __restrict__ mask, float* __restrict__ Mbuf)
{
    const int lane = threadIdx.x & 63;
    const int wid  = (blockIdx.x * 256 + threadIdx.x) >> 6;
    const int ul   = lane / 9;            // 7 units per wave, lane 63 idle
    const int i    = lane - ul * 9;
    const int unit = wid * 7 + ul;
    if (ul >= 7 || unit >= Bn * NC) return;
    const int b  = unit >> 5;             // unit / NC
    const int c  = unit & (NC - 1);
    const int t0 = 1 + c * CL;
    const int* mb = mask + b * Sn;
    if (!mb[t0]) return;                  // chunk fully beyond seq end

    float E[Ln][Ln];                      // exp(T[k][j]) — constants in regs
    #pragma unroll
    for (int k = 0; k < Ln; ++k)
        #pragma unroll
        for (int j = 0; j < Ln; ++j)
            E[k][j] = fexp2(T[k * Ln + j] * LOG2E);

    const float* eb = emis + (size_t)b * Sn * Ln;
    float P[Ln];                          // row i of running product, log2 domain
    {
        const float* er = eb + t0 * Ln;
        #pragma unroll
        for (int j = 0; j < Ln; ++j)
            P[j] = (T[i * Ln + j] + er[j]) * LOG2E;
    }

    const int tend = (t0 + CL < Sn) ? (t0 + CL) : Sn;
    int t = t0 + 1;
    int mcur = (t < tend) ? mb[t] : 0;
    float en[Ln];
    if (mcur) {
        const float* er = eb + t * Ln;
        #pragma unroll
        for (int j = 0; j < Ln; ++j) en[j] = er[j];
    }
    while (mcur) {
        const int t2 = t + 1;
        const int m2 = (t2 < tend) ? mb[t2] : 0;
        float e2[Ln];
        if (m2) {                          // prefetch next emission row
            const float* er = eb + t2 * Ln;
            #pragma unroll
            for (int j = 0; j < Ln; ++j) e2[j] = er[j];
        }
        float p = max9(P);
        float u[Ln];
        #pragma unroll
        for (int k = 0; k < Ln; ++k) u[k] = fexp2(P[k] - p);
        #pragma unroll
        for (int j = 0; j < Ln; ++j) {
            float a = u[0] * E[0][j];
            #pragma unroll
            for (int k = 1; k < Ln; ++k) a = fmaf(u[k], E[k][j], a);
            P[j] = fmaf(en[j], LOG2E, p + flog2(a));
        }
        t = t2; mcur = m2;
        #pragma unroll
        for (int j = 0; j < Ln; ++j) en[j] = e2[j];
    }

    float* o = Mbuf + ((size_t)(b * NC + c) * Ln + i) * Ln;
    #pragma unroll
    for (int j = 0; j < Ln; ++j) o[j] = P[j];
}

// ---------------- Kernel 2b: per-batch combine + score + logZ ----------------
__global__ __launch_bounds__(64) void combine_kernel(
    const float* __restrict__ emis, const float* __restrict__ st,
    const float* __restrict__ et,   const float* __restrict__ T,
    const int* __restrict__ labels, const int* __restrict__ mask,
    const float* __restrict__ Mbuf, float* __restrict__ llh)
{
    const int b = blockIdx.x, lane = threadIdx.x;
    const int* mb = mask + b * Sn;
    const int* lb = labels + b * Sn;
    const float* eb = emis + (size_t)b * Sn * Ln;

    int sl = 0;
    for (int t = lane; t < Sn; t += 64) sl += mb[t];
    #pragma unroll
    for (int off = 32; off; off >>= 1) sl += __shfl_xor(sl, off);

    float sc = 0.f;
    for (int t = lane; t < sl; t += 64) {
        int lt = lb[t];
        sc += eb[t * Ln + lt];
        if (t >= 1) sc += T[lb[t - 1] * Ln + lt];
    }
    #pragma unroll
    for (int off = 32; off; off >>= 1) sc += __shfl_xor(sc, off);

    float al[Ln];                         // alpha, log2 domain, replicated per lane
    #pragma unroll
    for (int j = 0; j < Ln; ++j) al[j] = (st[j] + eb[j]) * LOG2E;

    const int nreal = (sl - 1 + CL - 1) / CL;   // >= 8 since sl >= 128
    const int j9 = lane < Ln ? lane : Ln - 1;
    const float* mcb = Mbuf + (size_t)b * NC * (Ln * Ln);

    float col[Ln];
    #pragma unroll
    for (int k = 0; k < Ln; ++k) col[k] = mcb[k * Ln + j9];
    for (int c = 0; c < nreal; ++c) {
        float nc[Ln];
        if (c + 1 < nreal) {              // prefetch next chunk's column
            const float* m2 = mcb + (c + 1) * (Ln * Ln);
            #pragma unroll
            for (int k = 0; k < Ln; ++k) nc[k] = m2[k * Ln + j9];
        }
        float s[Ln];
        #pragma unroll
        for (int k = 0; k < Ln; ++k) s[k] = al[k] + col[k];
        float p = max9(s);
        float sum = fexp2(s[0] - p);
        #pragma unroll
        for (int k = 1; k < Ln; ++k) sum += fexp2(s[k] - p);
        float aj = p + flog2(sum);        // lane j holds new alpha[j]
        #pragma unroll
        for (int k = 0; k < Ln; ++k) al[k] = __shfl(aj, k);
        #pragma unroll
        for (int k = 0; k < Ln; ++k) col[k] = nc[k];
    }

    float z[Ln];
    #pragma unroll
    for (int j = 0; j < Ln; ++j) z[j] = al[j] + et[j] * LOG2E;
    float p = max9(z);
    float sum = fexp2(z[0] - p);
    #pragma unroll
    for (int j = 1; j < Ln; ++j) sum += fexp2(z[j] - p);
    const float logZ = (p + flog2(sum)) * LN2;

    if (lane == 0)
        llh[b] = sc + st[lb[0]] + et[lb[sl - 1]] - logZ;
}

// ---------------- Kernel 3: loss = -mean(llh) ----------------
__global__ __launch_bounds__(64) void loss_kernel(const float* __restrict__ llh,
                                                  float* __restrict__ out)
{
    float v = llh[threadIdx.x];
    #pragma unroll
    for (int off = 32; off; off >>= 1) v += __shfl_xor(v, off);
    if (threadIdx.x == 0) out[0] = -v * (1.0f / 64.0f);
}

extern "C" void kernel_launch(void* const* d_in, const int* in_sizes, int n_in,
                              void* d_out, int out_size, void* d_ws, size_t ws_size,
                              hipStream_t stream) {
    const float* hidden = (const float*)d_in[0];
    const float* W      = (const float*)d_in[1];
    const float* bias   = (const float*)d_in[2];
    const float* st     = (const float*)d_in[3];
    const float* et     = (const float*)d_in[4];
    const float* T      = (const float*)d_in[5];
    const int*   labels = (const int*)d_in[6];
    const int*   mask   = (const int*)d_in[7];

    float* emis = (float*)d_ws;                           // 294912 floats
    float* Mbuf = emis + (size_t)Bn * Sn * Ln;            // 64*32*81 = 165888 floats
    float* llh  = Mbuf + (size_t)Bn * NC * Ln * Ln;       // 64 floats

    emis_kernel<<<1024, 256, 0, stream>>>(hidden, W, bias, emis);
    {
        const int units  = Bn * NC;                       // 2048 batch-chunks
        const int blocks = (units + 27) / 28;             // 7 units/wave * 4 waves
        chunk_kernel<<<blocks, 256, 0, stream>>>(emis, T, mask, Mbuf);
    }
    combine_kernel<<<Bn, 64, 0, stream>>>(emis, st, et, T, labels, mask, Mbuf, llh);
    loss_kernel<<<1, 64, 0, stream>>>(llh, (float*)d_out);
}

// Round 3
// 51.361 us; speedup vs baseline: 2.5424x; 1.4525x over previous
//
#include <hip/hip_runtime.h>
#include <hip/hip_bf16.h>

#define LOG2E 1.4426950408889634f
#define LN2   0.6931471805599453f

constexpr int Bn = 64, Sn = 512, Hn = 1024, Ln = 9;
constexpr int CL = 24;                 // emission steps per chunk
constexpr int NC = 22;                 // ceil((Sn-1)/CL) = 22 chunks max

__device__ __forceinline__ float fexp2(float x) {
    float r; asm("v_exp_f32 %0, %1" : "=v"(r) : "v"(x)); return r;
}
__device__ __forceinline__ float flog2(float x) {
    float r; asm("v_log_f32 %0, %1" : "=v"(r) : "v"(x)); return r;
}
__device__ __forceinline__ float max9(const float* s) {
    return fmaxf(fmaxf(fmaxf(s[0], s[1]), fmaxf(s[2], s[3])),
                 fmaxf(fmaxf(s[4], s[5]), fmaxf(s[6], fmaxf(s[7], s[8]))));
}

// ---------------- Kernel 1: emissions = hidden @ W^T + b  (32768 x 9) ----------------
// 2048 blocks x 256 thr = 8192 waves x 4 rows. ~90 VGPR -> 16 waves/CU, 2 exact passes.
// Reduce via LDS transpose ([64][37], stride 37 -> conflict-free), not 432 bpermutes.
__global__ __launch_bounds__(256) void emis_kernel(
    const float* __restrict__ hidden, const float* __restrict__ W,
    const float* __restrict__ bias, float* __restrict__ emis,
    float* __restrict__ out0)
{
    __shared__ float red[4][64][37];
    const int lane = threadIdx.x & 63;
    const int w    = threadIdx.x >> 6;
    const int r0   = (blockIdx.x * 4 + w) * 4;

    if (blockIdx.x == 0 && threadIdx.x == 0) out0[0] = 0.f;  // accumulator for crf

    float acc[4][Ln];
    #pragma unroll
    for (int r = 0; r < 4; ++r)
        #pragma unroll
        for (int l = 0; l < Ln; ++l) acc[r][l] = 0.f;

    #pragma unroll 1
    for (int p = 0; p < 4; ++p) {
        const int h0 = p * 256 + lane * 4;
        float4 wv[Ln];
        #pragma unroll
        for (int l = 0; l < Ln; ++l)
            wv[l] = *(const float4*)(W + l * Hn + h0);
        #pragma unroll
        for (int r = 0; r < 4; ++r) {
            float4 h = *(const float4*)(hidden + (size_t)(r0 + r) * Hn + h0);
            #pragma unroll
            for (int l = 0; l < Ln; ++l) {
                acc[r][l] = fmaf(h.x, wv[l].x, acc[r][l]);
                acc[r][l] = fmaf(h.y, wv[l].y, acc[r][l]);
                acc[r][l] = fmaf(h.z, wv[l].z, acc[r][l]);
                acc[r][l] = fmaf(h.w, wv[l].w, acc[r][l]);
            }
        }
    }

    #pragma unroll
    for (int r = 0; r < 4; ++r)
        #pragma unroll
        for (int l = 0; l < Ln; ++l)
            red[w][lane][r * Ln + l] = acc[r][l];
    __syncthreads();

    if (lane < 36) {
        float s0 = 0.f, s1 = 0.f, s2 = 0.f, s3 = 0.f;
        #pragma unroll 4
        for (int i = 0; i < 64; i += 4) {
            s0 += red[w][i + 0][lane];
            s1 += red[w][i + 1][lane];
            s2 += red[w][i + 2][lane];
            s3 += red[w][i + 3][lane];
        }
        const int r = lane / 9, l = lane - r * 9;
        emis[(size_t)(r0 + r) * Ln + l] = (s0 + s1) + (s2 + s3) + bias[l];
    }
}

// ---------------- Kernel 2: fused CRF (chunks + combine + score + loss) ----------------
// One block per batch, 256 thr (4 waves). All data in LDS after staging.
// Chunk phase: 22 units x 9 lanes, linear-domain u <- (u*E) o exp2(e*log2e - 4),
// renorm once at step 12; log2 at chunk end. Combine (wave 0) runs concurrently
// with score (waves 1-3). Block atomicAdds -llh/64 into out.
__global__ __launch_bounds__(256) void crf_kernel(
    const float* __restrict__ emis, const float* __restrict__ st,
    const float* __restrict__ et,   const float* __restrict__ T,
    const int* __restrict__ labels, const int* __restrict__ mask,
    float* __restrict__ out)
{
    __shared__ __align__(16) float e_lds[Sn * Ln];   // raw emissions, 18432 B
    __shared__ float M_lds[NC][Ln][10];              // chunk matrices (log2 domain)
    __shared__ float part[4];
    __shared__ int   sl_sh;

    const int b    = blockIdx.x;
    const int tid  = threadIdx.x;
    const int w    = tid >> 6;
    const int lane = tid & 63;

    // P0: stage emissions + E=exp(T) + sequence length
    {
        const float4* src = (const float4*)(emis + (size_t)b * Sn * Ln);
        float4* dst = (float4*)e_lds;
        for (int i = tid; i < (Sn * Ln) / 4; i += 256) dst[i] = src[i];
    }
    float E[Ln][Ln];
    #pragma unroll
    for (int k = 0; k < Ln; ++k)
        #pragma unroll
        for (int j = 0; j < Ln; ++j)
            E[k][j] = fexp2(T[k * Ln + j] * LOG2E);
    if (w == 3) {
        const int* mb = mask + b * Sn;
        int s = 0;
        #pragma unroll
        for (int r = 0; r < Sn / 64; ++r) s += mb[lane + r * 64];
        #pragma unroll
        for (int off = 32; off; off >>= 1) s += __shfl_xor(s, off);
        if (lane == 0) sl_sh = s;
    }
    __syncthreads();

    const int sl    = sl_sh;                    // >= 128 by construction
    const int nreal = (sl - 1 + CL - 1) / CL;   // chunks covering steps 1..sl-1

    // P1: chunk transfer matrices
    {
        const int ul = lane / 9;                // unit-in-wave 0..6 (lane 63 idle)
        const int i  = lane - ul * 9;           // row of the matrix
        const int c  = w * 7 + ul;
        const int t0 = 1 + c * CL;
        if (ul < 7 && c < nreal) {
            const int nst = min(CL, sl - t0);   // >= 1
            float u[Ln];
            {
                const float* e0 = e_lds + t0 * Ln;
                #pragma unroll
                for (int j = 0; j < Ln; ++j)
                    u[j] = E[i][j] * fexp2(fmaf(e0[j], LOG2E, -4.f));
            }
            float extra = 0.f;
            for (int s = 1; s < nst; ++s) {
                const float* es = e_lds + (t0 + s) * Ln;
                float qn[Ln];
                #pragma unroll
                for (int j = 0; j < Ln; ++j)
                    qn[j] = fexp2(fmaf(es[j], LOG2E, -4.f));
                float v[Ln];
                #pragma unroll
                for (int j = 0; j < Ln; ++j) {
                    float a = u[0] * E[0][j];
                    #pragma unroll
                    for (int k = 1; k < Ln; ++k) a = fmaf(u[k], E[k][j], a);
                    v[j] = a;
                }
                #pragma unroll
                for (int j = 0; j < Ln; ++j) u[j] = v[j] * qn[j];
                if (s == 12) {                  // exponent-range insurance
                    float m  = max9(u);
                    float iv = 1.f / m;
                    #pragma unroll
                    for (int j = 0; j < Ln; ++j) u[j] *= iv;
                    extra = flog2(m);
                }
            }
            #pragma unroll
            for (int j = 0; j < Ln; ++j)
                M_lds[c][i][j] = flog2(u[j]) + extra + 4.f * (float)nst;
        }
    }
    __syncthreads();

    // P2: wave 0 = combine; waves 1-3 = numerator score (disjoint SIMDs)
    float logZ = 0.f;
    if (w == 0) {
        const int j9 = lane < Ln ? lane : Ln - 1;
        float al[Ln];
        #pragma unroll
        for (int j = 0; j < Ln; ++j) al[j] = (st[j] + e_lds[j]) * LOG2E;
        for (int c = 0; c < nreal; ++c) {
            float s[Ln];
            #pragma unroll
            for (int k = 0; k < Ln; ++k) s[k] = al[k] + M_lds[c][k][j9];
            float p = max9(s);
            float sum = fexp2(s[0] - p);
            #pragma unroll
            for (int k = 1; k < Ln; ++k) sum += fexp2(s[k] - p);
            float aj = p + flog2(sum);          // lane j -> new alpha[j]
            #pragma unroll
            for (int k = 0; k < Ln; ++k) al[k] = __shfl(aj, k);
        }
        float z[Ln];
        #pragma unroll
        for (int j = 0; j < Ln; ++j) z[j] = al[j] + et[j] * LOG2E;
        float p = max9(z);
        float sum = fexp2(z[0] - p);
        #pragma unroll
        for (int j = 1; j < Ln; ++j) sum += fexp2(z[j] - p);
        logZ = (p + flog2(sum)) * LN2;
    } else {
        const int* lb = labels + b * Sn;
        float sc = 0.f;
        for (int t = (w - 1) * 64 + lane; t < sl; t += 192) {
            int lt = lb[t];
            sc += e_lds[t * Ln + lt];
            if (t >= 1) sc += T[lb[t - 1] * Ln + lt];
        }
        #pragma unroll
        for (int off = 32; off; off >>= 1) sc += __shfl_xor(sc, off);
        if (w == 1 && lane == 0) sc += st[lb[0]] + et[lb[sl - 1]];
        if (lane == 0) part[w - 1] = sc;
    }
    __syncthreads();

    if (w == 0 && lane == 0) {
        float llh = part[0] + part[1] + part[2] - logZ;
        atomicAdd(out, llh * (-1.f / 64.f));
    }
}

extern "C" void kernel_launch(void* const* d_in, const int* in_sizes, int n_in,
                              void* d_out, int out_size, void* d_ws, size_t ws_size,
                              hipStream_t stream) {
    const float* hidden = (const float*)d_in[0];
    const float* W      = (const float*)d_in[1];
    const float* bias   = (const float*)d_in[2];
    const float* st     = (const float*)d_in[3];
    const float* et     = (const float*)d_in[4];
    const float* T      = (const float*)d_in[5];
    const int*   labels = (const int*)d_in[6];
    const int*   mask   = (const int*)d_in[7];

    float* emis = (float*)d_ws;                 // 32768 * 9 floats
    float* outp = (float*)d_out;

    emis_kernel<<<2048, 256, 0, stream>>>(hidden, W, bias, emis, outp);
    crf_kernel<<<Bn, 256, 0, stream>>>(emis, st, et, T, labels, mask, outp);
}